// Round 4
// baseline (458.160 us; speedup 1.0000x reference)
//
#include <hip/hip_runtime.h>

#define ROW_LEN 128
#define NPAIR (129 * 129)   // (seq, uniq) pairs, each in [0,128]

// Kernel A: precompute MLP(feats(seq,uniq)) for all 16641 pairs -> table[p][32].
__global__ __launch_bounds__(256) void mlp_table_kernel(
    const float* __restrict__ W1, const float* __restrict__ b1,
    const float* __restrict__ W2, const float* __restrict__ b2,
    float* __restrict__ table)
{
    const int tid = blockIdx.x * 256 + threadIdx.x;
    if (tid >= NPAIR * 32) return;
    const int p = tid >> 5;
    const int j = tid & 31;
    const int seq  = p / 129;
    const int uniq = p % 129;
    const float f0 = (float)seq  * (1.0f / 128.0f);
    const float f1 = (float)uniq * (1.0f / 128.0f);
    const float f2 = (seq > 0) ? ((float)uniq / (float)seq) : 0.0f;

    float acc = b2[j];
    #pragma unroll
    for (int jj = 0; jj < 32; ++jj) {
        float h = b1[jj];                 // lane-uniform -> scalar loads
        h = fmaf(f0, W1[jj],      h);
        h = fmaf(f1, W1[32 + jj], h);
        h = fmaf(f2, W1[64 + jj], h);
        h = fmaxf(h, 0.0f);
        acc = fmaf(h, W2[jj * 32 + j], acc);
    }
    table[tid] = fmaxf(acc, 0.0f);
}

// Kernel B (R7, resubmitted after 2x infra timeout): persistent waves,
// BATCH-4 software pipeline.
// Theory: R5 was in-flight-limited (32 KB/CU outstanding -> 3.0 TB/s by
// Little's law). R6's prefetch failed because the table gather was issued
// NEWEST in the vmcnt queue -> waiting for it (vmcnt(0)) drained the HBM
// prefetches every row. This version keeps the queue clean:
//   steady state per batch k:
//     1. issue 4 gathers for batch k-1          (queue: [L_k x8, g x4])
//     2. issue 8 row-loads for batch k+1        (queue: [L_k x8, g x4, L x8])
//     3. 4x DS phases consume L_k               (waits vmcnt(18),(16),... oldest only)
//     4. wait gathers = vmcnt(8)                (never touches the prefetches)
//     5. store batch k-1 outputs
// In-flight >= 4 KB/wave = 128 KB/CU (4x R5). DS phase identical to R5
// (4x b128 zero + 2 atomicOr-rtn + ballots); R6's scattered clears and nt
// stores reverted to isolate the memory-pipeline variable.
struct Batch {
    int2 id[4];
    int2 mk[4];
};

__device__ __forceinline__ void load_batch(
    const int2* ids2, const int2* mk2v, long r0, long stride, long k, long B,
    int lane, Batch& b)
{
    #pragma unroll
    for (int j = 0; j < 4; ++j) {
        const long row = r0 + (k * 4 + j) * stride;
        if (row < B) {                      // wave-uniform branch
            b.id[j] = ids2[row * 64 + lane];
            b.mk[j] = mk2v[row * 64 + lane];
        } else {
            b.id[j] = make_int2(0, 0);
            b.mk[j] = make_int2(0, 0);
        }
    }
}

__device__ __forceinline__ void proc_batch(
    unsigned* mybm, int lane, long r0, long stride, long k, long B,
    const Batch& b, int* p)
{
    #pragma unroll
    for (int j = 0; j < 4; ++j) {
        const long row = r0 + (k * 4 + j) * stride;
        if (row >= B) { p[j] = 0; continue; }   // wave-uniform

        // re-zero own bitmap: 1024 words = 256 uint4 -> 4 ds_write_b128.
        // Same-wave LDS program order makes zero -> atomics -> next zero safe
        // (proven by R5/R6 passing with the identical reliance).
        uint4* z = (uint4*)mybm;
        #pragma unroll
        for (int i = 0; i < 4; ++i) z[lane + i * 64] = make_uint4(0u, 0u, 0u, 0u);

        const int2 id2 = b.id[j];
        const int2 mk2 = b.mk[j];
        int n0 = 0, n1 = 0;
        if (mk2.x != 0) {
            const unsigned t = (unsigned)id2.x, m = 1u << (t & 31u);
            n0 = ((atomicOr(&mybm[t >> 5], m) & m) == 0u);
        }
        if (mk2.y != 0) {
            const unsigned t = (unsigned)id2.y, m = 1u << (t & 31u);
            n1 = ((atomicOr(&mybm[t >> 5], m) & m) == 0u);
        }

        const unsigned long long s0 = __ballot(mk2.x != 0);
        const unsigned long long s1 = __ballot(mk2.y != 0);
        const unsigned long long u0 = __ballot(n0 != 0);
        const unsigned long long u1 = __ballot(n1 != 0);

        const int seq  = __popcll(s0) + __popcll(s1);
        const int uniq = __popcll(u0) + __popcll(u1);
        p[j] = seq * 129 + uniq;
    }
}

__device__ __forceinline__ void gather_batch(const float* __restrict__ table,
                                             int lane, const int* p, float* g)
{
    if (lane < 32) {
        #pragma unroll
        for (int j = 0; j < 4; ++j) g[j] = table[p[j] * 32 + lane];
    }
}

__device__ __forceinline__ void store_batch(float* __restrict__ out, int lane,
    long r0, long stride, long k, long B, const float* g)
{
    if (lane < 32) {
        #pragma unroll
        for (int j = 0; j < 4; ++j) {
            const long row = r0 + (k * 4 + j) * stride;
            if (row < B) out[row * 32 + lane] = g[j];
        }
    }
}

__global__ __launch_bounds__(256, 8) void rows_kernel(
    const int* __restrict__ ids, const int* __restrict__ amask,
    const float* __restrict__ table, float* __restrict__ out, int B)
{
    __shared__ unsigned bm[4][1024];   // one 4 KB bitmap per wave
    const int wave = threadIdx.x >> 6;
    const int lane = threadIdx.x & 63;
    unsigned* mybm = bm[wave];
    const int2* ids2 = (const int2*)ids;
    const int2* mk2v = (const int2*)amask;

    const long stride = (long)gridDim.x * 4;        // total waves
    const long r0 = (long)blockIdx.x * 4 + wave;    // this wave's first row
    const long nb = (((long)B + stride - 1) / stride + 3) / 4;  // batches
    if (nb <= 0 || r0 >= B) return;

    Batch bA, bBv;
    int p[4], pn[4];
    float g[4];

    // prologue: two batches of loads in flight, process batch 0
    load_batch(ids2, mk2v, r0, stride, 0, B, lane, bA);
    load_batch(ids2, mk2v, r0, stride, 1, B, lane, bBv);
    proc_batch(mybm, lane, r0, stride, 0, B, bA, p);

    long k = 1;
    for (; k + 1 < nb; k += 2) {
        // batch k: consume bBv, prefetch k+1 into bA
        gather_batch(table, lane, p, g);
        load_batch(ids2, mk2v, r0, stride, k + 1, B, lane, bA);
        proc_batch(mybm, lane, r0, stride, k, B, bBv, pn);
        store_batch(out, lane, r0, stride, k - 1, B, g);
        #pragma unroll
        for (int j = 0; j < 4; ++j) p[j] = pn[j];

        // batch k+1: consume bA, prefetch k+2 into bBv
        gather_batch(table, lane, p, g);
        load_batch(ids2, mk2v, r0, stride, k + 2, B, lane, bBv);
        proc_batch(mybm, lane, r0, stride, k + 1, B, bA, pn);
        store_batch(out, lane, r0, stride, k, B, g);
        #pragma unroll
        for (int j = 0; j < 4; ++j) p[j] = pn[j];
    }
    if (k < nb) {           // tail batch (k odd -> lives in bBv)
        gather_batch(table, lane, p, g);
        proc_batch(mybm, lane, r0, stride, k, B, bBv, pn);
        store_batch(out, lane, r0, stride, k - 1, B, g);
        #pragma unroll
        for (int j = 0; j < 4; ++j) p[j] = pn[j];
        ++k;
    }
    // final epilogue
    gather_batch(table, lane, p, g);
    store_batch(out, lane, r0, stride, k - 1, B, g);
}

extern "C" void kernel_launch(void* const* d_in, const int* in_sizes, int n_in,
                              void* d_out, int out_size, void* d_ws, size_t ws_size,
                              hipStream_t stream) {
    const int*   ids   = (const int*)d_in[0];
    const int*   amask = (const int*)d_in[1];
    const float* W1    = (const float*)d_in[2];
    const float* b1    = (const float*)d_in[3];
    const float* W2    = (const float*)d_in[4];
    const float* b2    = (const float*)d_in[5];
    float* out   = (float*)d_out;
    float* table = (float*)d_ws;       // NPAIR*32*4 = 2.13 MB of ws

    const int B = in_sizes[0] / ROW_LEN;              // 262144

    const int tblThreads = NPAIR * 32;
    mlp_table_kernel<<<(tblThreads + 255) / 256, 256, 0, stream>>>(W1, b1, W2, b2, table);

    // persistent grid: 2048 blocks = 8 blocks/CU x 256 CUs; 8192 waves,
    // each wave owns 32 rows = 8 batches of 4, pipelined 2 batches deep.
    int blocks = (B + 3) / 4;
    if (blocks > 2048) blocks = 2048;
    rows_kernel<<<blocks, 256, 0, stream>>>(ids, amask, table, out, B);
}

// Round 6
// 299.885 us; speedup vs baseline: 1.5278x; 1.5278x over previous
//
#include <hip/hip_runtime.h>

#define ROW_LEN 128
#define NPAIR (129 * 129)   // (seq, uniq) pairs, each in [0,128]

// Kernel A: precompute MLP(feats(seq,uniq)) for all 16641 pairs -> table[p][32].
__global__ __launch_bounds__(256) void mlp_table_kernel(
    const float* __restrict__ W1, const float* __restrict__ b1,
    const float* __restrict__ W2, const float* __restrict__ b2,
    float* __restrict__ table)
{
    const int tid = blockIdx.x * 256 + threadIdx.x;
    if (tid >= NPAIR * 32) return;
    const int p = tid >> 5;
    const int j = tid & 31;
    const int seq  = p / 129;
    const int uniq = p % 129;
    const float f0 = (float)seq  * (1.0f / 128.0f);
    const float f1 = (float)uniq * (1.0f / 128.0f);
    const float f2 = (seq > 0) ? ((float)uniq / (float)seq) : 0.0f;

    float acc = b2[j];
    #pragma unroll
    for (int jj = 0; jj < 32; ++jj) {
        float h = b1[jj];                 // lane-uniform -> scalar loads
        h = fmaf(f0, W1[jj],      h);
        h = fmaf(f1, W1[32 + jj], h);
        h = fmaf(f2, W1[64 + jj], h);
        h = fmaxf(h, 0.0f);
        acc = fmaf(h, W2[jj * 32 + j], acc);
    }
    table[tid] = fmaxf(acc, 0.0f);
}

// Kernel B (R8, resubmitted after infra timeout): batch-2 double-buffered
// pipeline, ALL state in named scalars.
// R7 post-mortem: WRITE_SIZE 12x, FETCH 2.4x -> the Batch/p[]/g[] arrays under
// the 64-VGPR cap of launch_bounds(256,8) were demoted to scratch; 730 MB of
// traffic at 2.8 TB/s = the measured 260 us. The pipeline itself RAISED
// delivered BW (1.87 -> 2.8 TB/s), confirming the Little's-law theory.
// This version keeps the schedule but is spill-proof:
//   - named int2 scalars for both buffers (no arrays anywhere)
//   - 32-bit element indices, wave-uniform strides
//   - per iter: issue 2 gathers (batch k-1), issue 4 prefetch loads (batch
//     k+1), proc batch k (waits vmcnt(6): oldest only), store gathers
//     (vmcnt(4): prefetches stay in flight). Gathers are always OLDER than
//     prefetches -> no wait ever drains the prefetch queue (R6's bug).
__device__ __forceinline__ int proc_row(unsigned* mybm, int lane, int2 id2, int2 mk2)
{
    // re-zero own bitmap: 1024 words = 256 uint4 -> 4 ds_write_b128.
    // Same-wave LDS program order: zero -> atomics -> next row's zero (R5-proven).
    uint4* z = (uint4*)mybm;
    #pragma unroll
    for (int i = 0; i < 4; ++i) z[lane + i * 64] = make_uint4(0u, 0u, 0u, 0u);

    int n0 = 0, n1 = 0;
    if (mk2.x != 0) {
        const unsigned t = (unsigned)id2.x, m = 1u << (t & 31u);
        n0 = ((atomicOr(&mybm[t >> 5], m) & m) == 0u);
    }
    if (mk2.y != 0) {
        const unsigned t = (unsigned)id2.y, m = 1u << (t & 31u);
        n1 = ((atomicOr(&mybm[t >> 5], m) & m) == 0u);
    }
    const unsigned long long s0 = __ballot(mk2.x != 0);
    const unsigned long long s1 = __ballot(mk2.y != 0);
    const unsigned long long u0 = __ballot(n0 != 0);
    const unsigned long long u1 = __ballot(n1 != 0);
    const int seq  = __popcll(s0) + __popcll(s1);
    const int uniq = __popcll(u0) + __popcll(u1);
    return seq * 129 + uniq;
}

__global__ __launch_bounds__(256, 8) void rows_kernel(
    const int* __restrict__ ids, const int* __restrict__ amask,
    const float* __restrict__ table, float* __restrict__ out, int B)
{
    __shared__ unsigned bm[4][1024];   // one 4 KB bitmap per wave
    const int wave = threadIdx.x >> 6;
    const int lane = threadIdx.x & 63;
    unsigned* mybm = bm[wave];
    const int2* ids2 = (const int2*)ids;
    const int2* mk2v = (const int2*)amask;

    const unsigned nw = gridDim.x * 4;             // total waves (8192)
    const unsigned w  = blockIdx.x * 4 + wave;     // wave id
    const unsigned S  = nw * 64;                   // int2-elems per row-step
    const unsigned OS = nw * 32;                   // out-elems per row-step
    // batches only when rows divide evenly (true for B=262144); else tail loop
    const unsigned nb = ((unsigned)B % (2u * nw) == 0u) ? (unsigned)B / (2u * nw) : 0u;

    unsigned li = w * 64 + lane;    // load index, row-step 0 (max 16.7M: fits u32)
    unsigned oi = w * 32 + lane;    // store index, row-step 0

    int2 xi0, xm0, xi1, xm1;        // buffer X (even batches)
    int2 yi0, ym0, yi1, ym1;        // buffer Y (odd batches)
    int p0 = 0, p1 = 0;
    float g0 = 0.0f, g1 = 0.0f;

    if (nb > 0) {
        // prologue: batch 0 -> X, batch 1 -> Y
        xi0 = ids2[li];          xm0 = mk2v[li];
        xi1 = ids2[li + S];      xm1 = mk2v[li + S];
        if (nb > 1) {
            yi0 = ids2[li + 2 * S]; ym0 = mk2v[li + 2 * S];
            yi1 = ids2[li + 3 * S]; ym1 = mk2v[li + 3 * S];
        }
        unsigned pf = li + 4 * S;   // next prefetch index (row-step 4)

        p0 = proc_row(mybm, lane, xi0, xm0);
        p1 = proc_row(mybm, lane, xi1, xm1);

        unsigned k = 1;
        for (; k + 1 < nb; k += 2) {
            // ---- batch k (Y); prefetch batch k+1 -> X ----
            if (lane < 32) { g0 = table[p0 * 32 + lane]; g1 = table[p1 * 32 + lane]; }
            xi0 = ids2[pf];     xm0 = mk2v[pf];
            xi1 = ids2[pf + S]; xm1 = mk2v[pf + S];
            pf += 2 * S;
            int q0 = proc_row(mybm, lane, yi0, ym0);
            int q1 = proc_row(mybm, lane, yi1, ym1);
            if (lane < 32) { out[oi] = g0; out[oi + OS] = g1; }   // vmcnt(4): X survives
            oi += 2 * OS;
            p0 = q0; p1 = q1;

            // ---- batch k+1 (X); prefetch batch k+2 -> Y ----
            if (lane < 32) { g0 = table[p0 * 32 + lane]; g1 = table[p1 * 32 + lane]; }
            if (k + 2 < nb) {
                yi0 = ids2[pf];     ym0 = mk2v[pf];
                yi1 = ids2[pf + S]; ym1 = mk2v[pf + S];
                pf += 2 * S;
            }
            q0 = proc_row(mybm, lane, xi0, xm0);
            q1 = proc_row(mybm, lane, xi1, xm1);
            if (lane < 32) { out[oi] = g0; out[oi + OS] = g1; }   // vmcnt(4): Y survives
            oi += 2 * OS;
            p0 = q0; p1 = q1;
        }
        if (k < nb) {   // tail batch (odd index -> lives in Y)
            if (lane < 32) { g0 = table[p0 * 32 + lane]; g1 = table[p1 * 32 + lane]; }
            int q0 = proc_row(mybm, lane, yi0, ym0);
            int q1 = proc_row(mybm, lane, yi1, ym1);
            if (lane < 32) { out[oi] = g0; out[oi + OS] = g1; }
            oi += 2 * OS;
            p0 = q0; p1 = q1;
        }
        // final gather + store for the last processed batch
        if (lane < 32) {
            out[oi]      = table[p0 * 32 + lane];
            out[oi + OS] = table[p1 * 32 + lane];
        }
    }

    // generic tail (only runs when B % (2*nw) != 0): simple R5-style per row
    for (unsigned row = w + nb * 2 * nw; row < (unsigned)B; row += nw) {
        const unsigned idx = row * 64 + lane;
        const int2 id2 = ids2[idx];
        const int2 mk2 = mk2v[idx];
        const int p = proc_row(mybm, lane, id2, mk2);
        if (lane < 32) out[row * 32 + lane] = table[p * 32 + lane];
    }
}

extern "C" void kernel_launch(void* const* d_in, const int* in_sizes, int n_in,
                              void* d_out, int out_size, void* d_ws, size_t ws_size,
                              hipStream_t stream) {
    const int*   ids   = (const int*)d_in[0];
    const int*   amask = (const int*)d_in[1];
    const float* W1    = (const float*)d_in[2];
    const float* b1    = (const float*)d_in[3];
    const float* W2    = (const float*)d_in[4];
    const float* b2    = (const float*)d_in[5];
    float* out   = (float*)d_out;
    float* table = (float*)d_ws;       // NPAIR*32*4 = 2.13 MB of ws

    const int B = in_sizes[0] / ROW_LEN;              // 262144

    const int tblThreads = NPAIR * 32;
    mlp_table_kernel<<<(tblThreads + 255) / 256, 256, 0, stream>>>(W1, b1, W2, b2, table);

    // persistent grid: 2048 blocks = 8 blocks/CU x 256 CUs; 8192 waves,
    // each wave owns 32 rows = 16 batches of 2, pipelined 2 batches deep.
    int blocks = (B + 3) / 4;
    if (blocks > 2048) blocks = 2048;
    rows_kernel<<<blocks, 256, 0, stream>>>(ids, amask, table, out, B);
}

// Round 7
// 287.699 us; speedup vs baseline: 1.5925x; 1.0424x over previous
//
#include <hip/hip_runtime.h>

#define ROW_LEN 128
#define NPAIR (129 * 129)   // (seq, uniq) pairs, each in [0,128]

// Kernel A: precompute MLP(feats(seq,uniq)) for all 16641 pairs -> table[p][32].
__global__ __launch_bounds__(256) void mlp_table_kernel(
    const float* __restrict__ W1, const float* __restrict__ b1,
    const float* __restrict__ W2, const float* __restrict__ b2,
    float* __restrict__ table)
{
    const int tid = blockIdx.x * 256 + threadIdx.x;
    if (tid >= NPAIR * 32) return;
    const int p = tid >> 5;
    const int j = tid & 31;
    const int seq  = p / 129;
    const int uniq = p % 129;
    const float f0 = (float)seq  * (1.0f / 128.0f);
    const float f1 = (float)uniq * (1.0f / 128.0f);
    const float f2 = (seq > 0) ? ((float)uniq / (float)seq) : 0.0f;

    float acc = b2[j];
    #pragma unroll
    for (int jj = 0; jj < 32; ++jj) {
        float h = b1[jj];                 // lane-uniform -> scalar loads
        h = fmaf(f0, W1[jj],      h);
        h = fmaf(f1, W1[32 + jj], h);
        h = fmaf(f2, W1[64 + jj], h);
        h = fmaxf(h, 0.0f);
        acc = fmaf(h, W2[jj * 32 + j], acc);
    }
    table[tid] = fmaxf(acc, 0.0f);
}

// Kernel B (R9): R5 structure + int4 (16 B/lane) loads -> 2 rows per wave.
// R8 post-mortem: spill fixed (WRITE back to 32.7k KB) but VGPR=20 proves the
// compiler sank the loads and deleted the double buffer; persistent loop also
// lost occupancy (66% vs 76%). R5's churn launch IS the prefetch engine:
// every new wave's first instructions are its loads. Keep that.
// Across R5/R7/R8, CU-side traffic/dur pegs ~3.2/2.7 TB/s with no pipe
// saturated. Discriminating variable this round: load WIDTH. m13's 6.3 TB/s
// ceiling used 16 B/lane; R5 used 8 B/lane. Here: int4 loads, one wave covers
// rows {2k, 2k+1} (lanes 0-31 hold row A, lanes 32-63 row B), processed
// sequentially against one 4 KB bitmap. Per-row DS work identical to R5
// (one 4x b128 zero + one predicated atomic phase). Stores: 256 B contiguous
// per wave (both rows). VMEM row-load instrs halved.
__device__ __forceinline__ int pass_row(unsigned* mybm, const int4& id,
                                        const int4& mk, bool act)
{
    int s = 0, u = 0;
    #pragma unroll
    for (int j = 0; j < 4; ++j) {
        const int t = (j == 0) ? id.x : (j == 1) ? id.y : (j == 2) ? id.z : id.w;
        const int m = (j == 0) ? mk.x : (j == 1) ? mk.y : (j == 2) ? mk.z : mk.w;
        const bool v = act && (m != 0);
        int nw = 0;
        if (v) {
            const unsigned tt = (unsigned)t, bit = 1u << (tt & 31u);
            nw = ((atomicOr(&mybm[tt >> 5], bit) & bit) == 0u);
        }
        s += __popcll(__ballot(v));
        u += __popcll(__ballot(nw != 0));
    }
    return s * 129 + u;   // table row index
}

__global__ __launch_bounds__(256, 8) void rows_kernel(
    const int* __restrict__ ids, const int* __restrict__ amask,
    const float* __restrict__ table, float* __restrict__ out, int B)
{
    __shared__ unsigned bm[4][1024];   // one 4 KB bitmap per wave
    const int wave = threadIdx.x >> 6;
    const int lane = threadIdx.x & 63;
    unsigned* mybm = bm[wave];

    const long rowA = ((long)blockIdx.x * 4 + wave) * 2;   // first row of pair
    if (rowA >= B) return;
    const long rowL = rowA + (lane >> 5);                  // row this lane holds

    // issue the pair's loads first: 1 KB per instruction, 2 KB in flight/wave.
    // int4 index: row r occupies int4[ r*32 .. r*32+31 ].
    const int4* ids4 = (const int4*)ids;
    const int4* mk4v = (const int4*)amask;
    int4 id = make_int4(0, 0, 0, 0);
    int4 mk = make_int4(0, 0, 0, 0);
    if (rowL < B) {
        const long v = rowA * 32 + lane;   // == rowL*32 + (lane&31)
        id = ids4[v];
        mk = mk4v[v];
    }

    // zero bitmap while loads are in flight (4x ds_write_b128)
    uint4* z = (uint4*)mybm;
    #pragma unroll
    for (int i = 0; i < 4; ++i) z[lane + i * 64] = make_uint4(0u, 0u, 0u, 0u);

    // pass A: lanes 0-31 (they hold row A's 128 tokens, 4 per lane)
    const int pA = pass_row(mybm, id, mk, lane < 32);

    // re-zero (same-wave DS program order: atomics above complete first)
    #pragma unroll
    for (int i = 0; i < 4; ++i) z[lane + i * 64] = make_uint4(0u, 0u, 0u, 0u);

    // pass B: lanes 32-63 (row B)
    const int pB = pass_row(mybm, id, mk, lane >= 32);

    // epilogue: table gather (two 128 B L2-hot segments), ONE contiguous
    // 256 B store per wave covering both rows: out[rowA*32 + lane].
    if (rowL < B) {
        const int p = (lane < 32) ? pA : pB;
        out[rowA * 32 + lane] = table[p * 32 + (lane & 31)];
    }
}

extern "C" void kernel_launch(void* const* d_in, const int* in_sizes, int n_in,
                              void* d_out, int out_size, void* d_ws, size_t ws_size,
                              hipStream_t stream) {
    const int*   ids   = (const int*)d_in[0];
    const int*   amask = (const int*)d_in[1];
    const float* W1    = (const float*)d_in[2];
    const float* b1    = (const float*)d_in[3];
    const float* W2    = (const float*)d_in[4];
    const float* b2    = (const float*)d_in[5];
    float* out   = (float*)d_out;
    float* table = (float*)d_ws;       // NPAIR*32*4 = 2.13 MB of ws

    const int B = in_sizes[0] / ROW_LEN;              // 262144

    const int tblThreads = NPAIR * 32;
    mlp_table_kernel<<<(tblThreads + 255) / 256, 256, 0, stream>>>(W1, b1, W2, b2, table);

    // 2 rows per wave, 4 waves per block -> 8 rows per block; churn launch
    // (fresh waves' first instrs are loads = natural cross-wave prefetch).
    const long pairs = ((long)B + 1) / 2;
    const int blocks = (int)((pairs + 3) / 4);
    rows_kernel<<<blocks, 256, 0, stream>>>(ids, amask, table, out, B);
}

// Round 11
// 283.175 us; speedup vs baseline: 1.6179x; 1.0160x over previous
//
#include <hip/hip_runtime.h>

#define ROW_LEN 128
#define NPAIR (129 * 129)   // (seq, uniq) pairs, each in [0,128]

// Kernel A: precompute MLP(feats(seq,uniq)) for all 16641 pairs -> table[p][32].
__global__ __launch_bounds__(256) void mlp_table_kernel(
    const float* __restrict__ W1, const float* __restrict__ b1,
    const float* __restrict__ W2, const float* __restrict__ b2,
    float* __restrict__ table)
{
    const int tid = blockIdx.x * 256 + threadIdx.x;
    if (tid >= NPAIR * 32) return;
    const int p = tid >> 5;
    const int j = tid & 31;
    const int seq  = p / 129;
    const int uniq = p % 129;
    const float f0 = (float)seq  * (1.0f / 128.0f);
    const float f1 = (float)uniq * (1.0f / 128.0f);
    const float f2 = (seq > 0) ? ((float)uniq / (float)seq) : 0.0f;

    float acc = b2[j];
    #pragma unroll
    for (int jj = 0; jj < 32; ++jj) {
        float h = b1[jj];                 // lane-uniform -> scalar loads
        h = fmaf(f0, W1[jj],      h);
        h = fmaf(f1, W1[32 + jj], h);
        h = fmaf(f2, W1[64 + jj], h);
        h = fmaxf(h, 0.0f);
        acc = fmaf(h, W2[jj * 32 + j], acc);
    }
    table[tid] = fmaxf(acc, 0.0f);
}

// Kernel B (R10, resubmitted 3x after infra timeouts): 2 rows per wave, ONE
// concurrent DS phase via pair-bitmap.
// R9 post-mortem: int4 loads fine, but two SEQUENTIAL bitmap passes doubled
// the per-row dependent chain -> 97 us. Across R5-R9 no pipe saturates;
// the limiter is (per-row serial chain) / (wave concurrency).
// This version: lanes 0-31 hold row A (4 tokens each), lanes 32-63 row B.
// Both rows share one bitmap with 2 bits per token value:
//     word = token >> 4, bit = ((token & 15) << 1) | (lane >= 32)
// -> 32000 tokens * 2 bits = 8 KB per wave. ONE zero phase (8x ds_write_b128
// = same per-row zero cost as R5) + ONE atomic phase (4 atomics/lane, all 64
// lanes concurrent) serve BOTH rows. Ballots count both rows at once
// (popc of lo/hi 32 bits). Per row vs R5: VMEM instrs halved, DS phases
// halved, VALU equal. Cost: 32 KB LDS/block -> 5 blocks/CU -> 20 waves/CU.
__global__ __launch_bounds__(256, 5) void rows_kernel(
    const int* __restrict__ ids, const int* __restrict__ amask,
    const float* __restrict__ table, float* __restrict__ out, int B)
{
    __shared__ unsigned bm[4][2048];   // 8 KB pair-bitmap per wave (32 KB/block)
    const int wave = threadIdx.x >> 6;
    const int lane = threadIdx.x & 63;
    unsigned* mybm = bm[wave];

    const long rowA = ((long)blockIdx.x * 4 + wave) * 2;   // first row of pair
    if (rowA >= B) return;
    const long rowL = rowA + (lane >> 5);                  // row this lane holds

    // issue the pair's loads first (1 KB per instruction, 2 KB in flight/wave)
    const int4* ids4 = (const int4*)ids;
    const int4* mk4v = (const int4*)amask;
    int4 id = make_int4(0, 0, 0, 0);
    int4 mk = make_int4(0, 0, 0, 0);
    if (rowL < B) {
        const long v = rowA * 32 + lane;   // == rowL*32 + (lane&31)
        id = ids4[v];
        mk = mk4v[v];
    }

    // zero the 8 KB pair-bitmap while loads are in flight:
    // 2048 words = 512 uint4 -> 8 ds_write_b128 per lane (== R5's per-row rate)
    uint4* z = (uint4*)mybm;
    #pragma unroll
    for (int i = 0; i < 8; ++i) z[lane + i * 64] = make_uint4(0u, 0u, 0u, 0u);

    const unsigned rowbit = (lane >= 32) ? 1u : 0u;
    int seqA = 0, seqB = 0, uniqA = 0, uniqB = 0;
    #pragma unroll
    for (int j = 0; j < 4; ++j) {
        const int t = (j == 0) ? id.x : (j == 1) ? id.y : (j == 2) ? id.z : id.w;
        const int m = (j == 0) ? mk.x : (j == 1) ? mk.y : (j == 2) ? mk.z : mk.w;
        const bool v = (m != 0);
        int nw = 0;
        if (v) {
            const unsigned tt  = (unsigned)t;
            const unsigned bit = ((tt & 15u) << 1) | rowbit;
            const unsigned msk = 1u << bit;
            nw = ((atomicOr(&mybm[tt >> 4], msk) & msk) == 0u);
        }
        // one ballot pair serves BOTH rows: lo 32 lanes = row A, hi = row B
        const unsigned long long vb = __ballot(v);
        const unsigned long long nb = __ballot(nw != 0);
        seqA  += __popc((unsigned)vb);
        seqB  += __popc((unsigned)(vb >> 32));
        uniqA += __popc((unsigned)nb);
        uniqB += __popc((unsigned)(nb >> 32));
    }
    const int pA = seqA * 129 + uniqA;
    const int pB = seqB * 129 + uniqB;

    // epilogue: two 128 B L2-hot table segments, ONE contiguous 256 B store
    if (rowL < B) {
        const int p = (lane < 32) ? pA : pB;
        out[rowA * 32 + lane] = table[p * 32 + (lane & 31)];
    }
}

extern "C" void kernel_launch(void* const* d_in, const int* in_sizes, int n_in,
                              void* d_out, int out_size, void* d_ws, size_t ws_size,
                              hipStream_t stream) {
    const int*   ids   = (const int*)d_in[0];
    const int*   amask = (const int*)d_in[1];
    const float* W1    = (const float*)d_in[2];
    const float* b1    = (const float*)d_in[3];
    const float* W2    = (const float*)d_in[4];
    const float* b2    = (const float*)d_in[5];
    float* out   = (float*)d_out;
    float* table = (float*)d_ws;       // NPAIR*32*4 = 2.13 MB of ws

    const int B = in_sizes[0] / ROW_LEN;              // 262144

    const int tblThreads = NPAIR * 32;
    mlp_table_kernel<<<(tblThreads + 255) / 256, 256, 0, stream>>>(W1, b1, W2, b2, table);

    // 2 rows per wave, 4 waves per block -> 8 rows per block; churn launch
    // (fresh waves' first instructions are their loads = natural prefetch).
    const long pairs = ((long)B + 1) / 2;
    const int blocks = (int)((pairs + 3) / 4);
    rows_kernel<<<blocks, 256, 0, stream>>>(ids, amask, table, out, B);
}